// Round 1
// baseline (2916.600 us; speedup 1.0000x reference)
//
#include <hip/hip_runtime.h>
#include <hip/hip_bf16.h>
#include <math.h>

#define EMBED 1024
#define HEADS 16
#define HDIM  64
#define SEQ   2048
#define BATCH 4

// ---------------------------------------------------------------------------
// GEMM: out = A @ W^T (+ bias), A [M,K] row-major, W [N,K] row-major ("NT").
// MODE 0: scatter output to [B,H,S,D] (QKV projections, no bias)
// MODE 1: row-major [M,N] + bias (output projection)
// 64x64 tile, BK=16, 256 threads, 4x4 per thread.
// ---------------------------------------------------------------------------
template <int MODE>
__global__ __launch_bounds__(256) void gemm_nt(const float* __restrict__ A,
                                               const float* __restrict__ W,
                                               float* __restrict__ out,
                                               const float* __restrict__ bias,
                                               int M, int N, int K) {
    __shared__ float As[16][68];  // [k][m], pad 4 -> float4-aligned rows, ~2-way max
    __shared__ float Ws[16][68];  // [k][n]

    const int tid = threadIdx.x;
    const int tx = tid & 15;        // output col group
    const int ty = tid >> 4;        // output row group
    const int m0 = blockIdx.y * 64;
    const int n0 = blockIdx.x * 64;

    const int lr  = tid >> 2;       // 0..63 : tile row for loading
    const int lk4 = tid & 3;        // 0..3  : which float4 along k

    const float* Arow = A + (size_t)(m0 + lr) * K + lk4 * 4;
    const float* Wrow = W + (size_t)(n0 + lr) * K + lk4 * 4;

    float acc[4][4] = {};

    for (int k0 = 0; k0 < K; k0 += 16) {
        float4 av = *(const float4*)(Arow + k0);
        float4 wv = *(const float4*)(Wrow + k0);
        __syncthreads();  // previous tile's compute done before overwrite
        As[lk4 * 4 + 0][lr] = av.x;
        As[lk4 * 4 + 1][lr] = av.y;
        As[lk4 * 4 + 2][lr] = av.z;
        As[lk4 * 4 + 3][lr] = av.w;
        Ws[lk4 * 4 + 0][lr] = wv.x;
        Ws[lk4 * 4 + 1][lr] = wv.y;
        Ws[lk4 * 4 + 2][lr] = wv.z;
        Ws[lk4 * 4 + 3][lr] = wv.w;
        __syncthreads();
#pragma unroll
        for (int kk = 0; kk < 16; ++kk) {
            float4 a = *(const float4*)&As[kk][ty * 4];
            float4 w = *(const float4*)&Ws[kk][tx * 4];
            float aa[4] = {a.x, a.y, a.z, a.w};
            float ww[4] = {w.x, w.y, w.z, w.w};
#pragma unroll
            for (int i = 0; i < 4; ++i)
#pragma unroll
                for (int j = 0; j < 4; ++j) acc[i][j] += aa[i] * ww[j];
        }
    }

    if (MODE == 0) {
        // n0 is a multiple of 64 -> whole block belongs to one head
        const int h = n0 >> 6;
#pragma unroll
        for (int i = 0; i < 4; ++i) {
            int m = m0 + ty * 4 + i;
            int b = m >> 11;          // S = 2048
            int s = m & (SEQ - 1);
            float4 o = make_float4(acc[i][0], acc[i][1], acc[i][2], acc[i][3]);
            *(float4*)&out[(((size_t)b * HEADS + h) * SEQ + s) * HDIM + tx * 4] = o;
        }
    } else {
        float4 bv = *(const float4*)&bias[n0 + tx * 4];
#pragma unroll
        for (int i = 0; i < 4; ++i) {
            int m = m0 + ty * 4 + i;
            float4 o = make_float4(acc[i][0] + bv.x, acc[i][1] + bv.y,
                                   acc[i][2] + bv.z, acc[i][3] + bv.w);
            *(float4*)&out[(size_t)m * N + n0 + tx * 4] = o;
        }
    }
}

// ---------------------------------------------------------------------------
// Flash attention (causal), fp32. Q/K/V in [B,H,S,D]. Output -> att [B,S,E].
// One block (256 thr) per (bh, 64-query tile). Online softmax.
// Thread t: row r = t/4 (0..63), group g = t%4.
//   QK^T: thread computes scores for cols c = i*4+g (i=0..15)
//   PV  : thread accumulates dims d = g*16 + i (i=0..15)
// ---------------------------------------------------------------------------
__global__ __launch_bounds__(256) void attn_fwd(const float* __restrict__ Q,
                                                const float* __restrict__ K,
                                                const float* __restrict__ V,
                                                float* __restrict__ att) {
    __shared__ float Qs[64][68];
    __shared__ float Ks[64][68];
    __shared__ float Vs[64][68];

    const int tid = threadIdx.x;
    const int bh  = blockIdx.y;
    const int q0  = blockIdx.x * 64;
    const int r   = tid >> 2;  // 0..63
    const int g   = tid & 3;   // 0..3

    const size_t base = (size_t)bh * SEQ * HDIM;

    // load Q tile (64 rows x 64 dims) as float4s
    for (int idx = tid; idx < 64 * 16; idx += 256) {
        int row = idx >> 4, d4 = idx & 15;
        *(float4*)&Qs[row][d4 * 4] =
            *(const float4*)(Q + base + (size_t)(q0 + row) * HDIM + d4 * 4);
    }

    float acc[16] = {};
    float m_run = -INFINITY, l_run = 0.f;
    const int qg = q0 + r;
    const int ntiles = blockIdx.x + 1;  // causal: k-tiles with k0 <= q0

    for (int kt = 0; kt < ntiles; ++kt) {
        const int k0 = kt * 64;
        __syncthreads();
        for (int idx = tid; idx < 64 * 16; idx += 256) {
            int row = idx >> 4, d4 = idx & 15;
            *(float4*)&Ks[row][d4 * 4] =
                *(const float4*)(K + base + (size_t)(k0 + row) * HDIM + d4 * 4);
            *(float4*)&Vs[row][d4 * 4] =
                *(const float4*)(V + base + (size_t)(k0 + row) * HDIM + d4 * 4);
        }
        __syncthreads();

        float p[16];
        float mloc = -INFINITY;
#pragma unroll
        for (int i = 0; i < 16; ++i) {
            int c = i * 4 + g;
            float s;
            if (k0 + c <= qg) {
                float dot = 0.f;
#pragma unroll
                for (int d4 = 0; d4 < 16; ++d4) {
                    float4 qv = *(const float4*)&Qs[r][d4 * 4];
                    float4 kv = *(const float4*)&Ks[c][d4 * 4];
                    dot += qv.x * kv.x + qv.y * kv.y + qv.z * kv.z + qv.w * kv.w;
                }
                s = dot * 0.125f;  // 1/sqrt(64)
            } else {
                s = -INFINITY;
            }
            p[i] = s;
            mloc = fmaxf(mloc, s);
        }
        // row max across the 4 sibling lanes
        mloc = fmaxf(mloc, __shfl_xor(mloc, 1));
        mloc = fmaxf(mloc, __shfl_xor(mloc, 2));
        float m_new = fmaxf(m_run, mloc);       // finite from first tile on
        float scale = __expf(m_run - m_new);    // 0 on first tile

        float psum = 0.f;
#pragma unroll
        for (int i = 0; i < 16; ++i) {
            p[i] = __expf(p[i] - m_new);  // masked -> exp(-inf)=0
            psum += p[i];
        }
        psum += __shfl_xor(psum, 1);
        psum += __shfl_xor(psum, 2);
        l_run = l_run * scale + psum;
        m_run = m_new;

#pragma unroll
        for (int i = 0; i < 16; ++i) acc[i] *= scale;

        // PV: acc[d] += sum_k P[r][k] * V[k][d]
        const int lanebase = (tid & 63) & ~3;
#pragma unroll
        for (int k = 0; k < 64; ++k) {
            float pv = __shfl(p[k >> 2], lanebase | (k & 3));
#pragma unroll
            for (int i4 = 0; i4 < 4; ++i4) {
                float4 v = *(const float4*)&Vs[k][g * 16 + i4 * 4];
                acc[i4 * 4 + 0] += pv * v.x;
                acc[i4 * 4 + 1] += pv * v.y;
                acc[i4 * 4 + 2] += pv * v.z;
                acc[i4 * 4 + 3] += pv * v.w;
            }
        }
    }

    const float inv = 1.f / l_run;
    const int b = bh >> 4, h = bh & 15;
    float* dst = att + ((size_t)b * SEQ + (q0 + r)) * EMBED + h * HDIM + g * 16;
#pragma unroll
    for (int i4 = 0; i4 < 4; ++i4) {
        float4 o = make_float4(acc[i4 * 4 + 0] * inv, acc[i4 * 4 + 1] * inv,
                               acc[i4 * 4 + 2] * inv, acc[i4 * 4 + 3] * inv);
        *(float4*)(dst + i4 * 4) = o;
    }
}

// ---------------------------------------------------------------------------
extern "C" void kernel_launch(void* const* d_in, const int* in_sizes, int n_in,
                              void* d_out, int out_size, void* d_ws, size_t ws_size,
                              hipStream_t stream) {
    const float* x  = (const float*)d_in[0];
    const float* Wq = (const float*)d_in[1];
    const float* Wk = (const float*)d_in[2];
    const float* Wv = (const float*)d_in[3];
    const float* Wo = (const float*)d_in[4];
    const float* bo = (const float*)d_in[5];
    float* out = (float*)d_out;

    const int M = BATCH * SEQ;  // 8192
    const int N = EMBED;        // 1024
    const int Kd = EMBED;       // 1024

    // workspace: Q, K, V in [B,H,S,D] + att in [B,S,E]  (4 x 32 MB = 128 MB)
    const size_t P = (size_t)BATCH * HEADS * SEQ * HDIM;  // 8M elements
    float* ws  = (float*)d_ws;
    float* Qb  = ws;
    float* Kb  = ws + P;
    float* Vb  = ws + 2 * P;
    float* att = ws + 3 * P;

    dim3 gblk(N / 64, M / 64);  // (16, 128)
    gemm_nt<0><<<gblk, 256, 0, stream>>>(x, Wq, Qb, nullptr, M, N, Kd);
    gemm_nt<0><<<gblk, 256, 0, stream>>>(x, Wk, Kb, nullptr, M, N, Kd);
    gemm_nt<0><<<gblk, 256, 0, stream>>>(x, Wv, Vb, nullptr, M, N, Kd);

    attn_fwd<<<dim3(SEQ / 64, BATCH * HEADS), 256, 0, stream>>>(Qb, Kb, Vb, att);

    gemm_nt<1><<<gblk, 256, 0, stream>>>(att, Wo, out, bo, M, N, Kd);
}

// Round 2
// 377.090 us; speedup vs baseline: 7.7345x; 7.7345x over previous
//
#include <hip/hip_runtime.h>
#include <math.h>

#define EMBED 1024
#define HEADS 16
#define HDIM  64
#define SEQ   2048
#define BATCH 4

typedef __attribute__((ext_vector_type(8))) short short8;
typedef __attribute__((ext_vector_type(4))) float f32x4;

__device__ __forceinline__ unsigned short f2b(float f) {
    union { float f; unsigned int u; } c; c.f = f;
    unsigned int r = (c.u + 0x7fffu + ((c.u >> 16) & 1u)) >> 16;
    return (unsigned short)r;
}

__device__ __forceinline__ void gld16(const void* g, void* l) {
    __builtin_amdgcn_global_load_lds((__attribute__((address_space(1))) void*)g,
                                     (__attribute__((address_space(3))) void*)l,
                                     16, 0, 0);
}

// fp32 -> bf16 (RNE), 8 elems/thread
__global__ __launch_bounds__(256) void cast_bf16(const float* __restrict__ src,
                                                 unsigned short* __restrict__ dst,
                                                 int n) {
    int i = (blockIdx.x * 256 + threadIdx.x) * 8;
    if (i >= n) return;
    float4 a = *(const float4*)(src + i);
    float4 b = *(const float4*)(src + i + 4);
    short8 v;
    v[0] = (short)f2b(a.x); v[1] = (short)f2b(a.y);
    v[2] = (short)f2b(a.z); v[3] = (short)f2b(a.w);
    v[4] = (short)f2b(b.x); v[5] = (short)f2b(b.y);
    v[6] = (short)f2b(b.z); v[7] = (short)f2b(b.w);
    *(short8*)(dst + i) = v;
}

// ---------------------------------------------------------------------------
// bf16 MFMA GEMM (NT): out = A @ W^T, A [M,K], W [N,K], both row-major bf16.
// 128x128 tile, BK=32, 4 waves (2x2 of 64x64), 16x16x32 MFMA, fp32 acc.
// MODE 0: scatter bf16 to [B,H,S,D], scaled by oscale.  MODE 1: fp32 [M,N]+bias.
// ---------------------------------------------------------------------------
template <int MODE>
__global__ __launch_bounds__(256) void gemm_bf16(const unsigned short* __restrict__ A,
                                                 const unsigned short* __restrict__ W,
                                                 void* __restrict__ outp,
                                                 const float* __restrict__ bias,
                                                 float oscale) {
    const int M_ = BATCH * SEQ, N_ = EMBED, K_ = EMBED;
    (void)M_;
    __shared__ __attribute__((aligned(16))) unsigned short As[128 * 32];
    __shared__ __attribute__((aligned(16))) unsigned short Bs[128 * 32];

    const int tid  = threadIdx.x;
    const int lane = tid & 63;
    const int w    = tid >> 6;
    const int wr   = w >> 1, wc = w & 1;
    const int m0 = blockIdx.y * 128, n0 = blockIdx.x * 128;

    // staging: wave w covers rows w*32 .. w*32+31 of each tile, 2 instrs each
    const unsigned short* gA = A + (size_t)(m0 + w * 32 + (lane >> 2)) * K_ + (lane & 3) * 8;
    const unsigned short* gB = W + (size_t)(n0 + w * 32 + (lane >> 2)) * K_ + (lane & 3) * 8;
    unsigned short* lA = As + (w * 32) * 32;  // wave-uniform LDS base
    unsigned short* lB = Bs + (w * 32) * 32;

    f32x4 zero = {0.f, 0.f, 0.f, 0.f};
    f32x4 acc[4][4];
#pragma unroll
    for (int i = 0; i < 4; ++i)
#pragma unroll
        for (int j = 0; j < 4; ++j) acc[i][j] = zero;

    for (int k0 = 0; k0 < K_; k0 += 32) {
        gld16(gA, lA);
        gld16(gA + (size_t)16 * K_, lA + 16 * 32);
        gld16(gB, lB);
        gld16(gB + (size_t)16 * K_, lB + 16 * 32);
        gA += 32; gB += 32;
        __syncthreads();  // drains vmcnt -> LDS data landed
        short8 af[4], bfr[4];
#pragma unroll
        for (int i = 0; i < 4; ++i) {
            af[i]  = *(const short8*)&As[(wr * 64 + i * 16 + (lane & 15)) * 32 + (lane >> 4) * 8];
            bfr[i] = *(const short8*)&Bs[(wc * 64 + i * 16 + (lane & 15)) * 32 + (lane >> 4) * 8];
        }
#pragma unroll
        for (int i = 0; i < 4; ++i)
#pragma unroll
            for (int j = 0; j < 4; ++j)
                acc[i][j] = __builtin_amdgcn_mfma_f32_16x16x32_bf16(af[i], bfr[j], acc[i][j], 0, 0, 0);
        __syncthreads();  // compute done before next overwrite
    }

    // C/D layout: col = lane&15, row = (lane>>4)*4 + j
    if (MODE == 0) {
        unsigned short* dst = (unsigned short*)outp;
#pragma unroll
        for (int i = 0; i < 4; ++i)
#pragma unroll
            for (int ni = 0; ni < 4; ++ni) {
                int n = n0 + wc * 64 + ni * 16 + (lane & 15);
                int h = n >> 6, d = n & 63;
#pragma unroll
                for (int j = 0; j < 4; ++j) {
                    int m = m0 + wr * 64 + i * 16 + (lane >> 4) * 4 + j;
                    int b = m >> 11, s = m & (SEQ - 1);
                    dst[(((size_t)b * HEADS + h) * SEQ + s) * HDIM + d] =
                        f2b(acc[i][ni][j] * oscale);
                }
            }
    } else {
        float* dst = (float*)outp;
#pragma unroll
        for (int i = 0; i < 4; ++i)
#pragma unroll
            for (int ni = 0; ni < 4; ++ni) {
                int n = n0 + wc * 64 + ni * 16 + (lane & 15);
                float bv = bias[n];
#pragma unroll
                for (int j = 0; j < 4; ++j) {
                    int m = m0 + wr * 64 + i * 16 + (lane >> 4) * 4 + j;
                    dst[(size_t)m * N_ + n] = acc[i][ni][j] + bv;
                }
            }
    }
}

// ---------------------------------------------------------------------------
// MFMA flash attention (causal). Q pre-scaled by 1/sqrt(D) at projection.
// Block = 4 waves x 16 q-rows (QBLK 64); KV tile = 64. bf16 in, bf16 out.
// ---------------------------------------------------------------------------
__global__ __launch_bounds__(256) void attn_mfma(const unsigned short* __restrict__ Q,
                                                 const unsigned short* __restrict__ K,
                                                 const unsigned short* __restrict__ V,
                                                 unsigned short* __restrict__ att) {
    __shared__ __attribute__((aligned(16))) short Ks[64][72];     // [k][d], +8 pad
    __shared__ __attribute__((aligned(16))) short Vt[64][72];     // [d][k], +8 pad
    __shared__ __attribute__((aligned(16))) short Ps[4][16][72];  // per-wave P

    const int tid  = threadIdx.x;
    const int lane = tid & 63;
    const int w    = tid >> 6;
    const int qt   = blockIdx.x;
    const int bh   = blockIdx.y;
    const int q0   = qt * 64;
    const size_t base = (size_t)bh * SEQ * HDIM;

    // Q fragments (A-operand: row = lane&15, k = (lane>>4)*8+e)
    const unsigned short* qp =
        Q + base + (size_t)(q0 + w * 16 + (lane & 15)) * HDIM + (lane >> 4) * 8;
    short8 qf0 = *(const short8*)qp;
    short8 qf1 = *(const short8*)(qp + 32);

    f32x4 zero = {0.f, 0.f, 0.f, 0.f};
    f32x4 o[4];
    float m_run[4], l_run[4];
#pragma unroll
    for (int i = 0; i < 4; ++i) { o[i] = zero; m_run[i] = -INFINITY; l_run[i] = 0.f; }

    const int vrow = lane;
    const int vdb  = w * 16;

    for (int kt = 0; kt <= qt; ++kt) {
        const int k0 = kt * 64;
        __syncthreads();  // previous tile's reads done
        // stage K tile [64][64]
        for (int c = tid; c < 512; c += 256) {
            int r = c >> 3, col = (c & 7) * 8;
            *(short8*)&Ks[r][col] = *(const short8*)(K + base + (size_t)(k0 + r) * HDIM + col);
        }
        // stage V transposed: Vt[d][k] = V[k][d]
        {
            const unsigned short* vp = V + base + (size_t)(k0 + vrow) * HDIM + vdb;
            short8 v0 = *(const short8*)vp;
            short8 v1 = *(const short8*)(vp + 8);
#pragma unroll
            for (int jj = 0; jj < 8; ++jj) {
                Vt[vdb + jj][vrow]     = v0[jj];
                Vt[vdb + 8 + jj][vrow] = v1[jj];
            }
        }
        __syncthreads();

        // QK^T: S[16 q][64 k] in 4 chunks of 16x16
        f32x4 sc[4];
#pragma unroll
        for (int c = 0; c < 4; ++c) {
            short8 kf0 = *(const short8*)&Ks[c * 16 + (lane & 15)][(lane >> 4) * 8];
            short8 kf1 = *(const short8*)&Ks[c * 16 + (lane & 15)][32 + (lane >> 4) * 8];
            sc[c] = __builtin_amdgcn_mfma_f32_16x16x32_bf16(qf0, kf0, zero, 0, 0, 0);
            sc[c] = __builtin_amdgcn_mfma_f32_16x16x32_bf16(qf1, kf1, sc[c], 0, 0, 0);
        }

        if (kt == qt) {  // diagonal tile: causal mask (k0 == q0)
#pragma unroll
            for (int c = 0; c < 4; ++c)
#pragma unroll
                for (int j = 0; j < 4; ++j) {
                    int row = w * 16 + (lane >> 4) * 4 + j;
                    int col = c * 16 + (lane & 15);
                    if (col > row) sc[c][j] = -INFINITY;
                }
        }

        // online softmax (row r = (lane>>4)*4+j spread over 16 lanes)
        float mloc[4], scl[4], ps[4];
#pragma unroll
        for (int j = 0; j < 4; ++j)
            mloc[j] = fmaxf(fmaxf(sc[0][j], sc[1][j]), fmaxf(sc[2][j], sc[3][j]));
#pragma unroll
        for (int j = 0; j < 4; ++j) {
            mloc[j] = fmaxf(mloc[j], __shfl_xor(mloc[j], 1));
            mloc[j] = fmaxf(mloc[j], __shfl_xor(mloc[j], 2));
            mloc[j] = fmaxf(mloc[j], __shfl_xor(mloc[j], 4));
            mloc[j] = fmaxf(mloc[j], __shfl_xor(mloc[j], 8));
            float mnew = fmaxf(m_run[j], mloc[j]);
            scl[j] = __expf(m_run[j] - mnew);
            m_run[j] = mnew;
            ps[j] = 0.f;
        }
#pragma unroll
        for (int c = 0; c < 4; ++c)
#pragma unroll
            for (int j = 0; j < 4; ++j) {
                float p = __expf(sc[c][j] - m_run[j]);  // masked -> exp(-inf)=0
                sc[c][j] = p;
                ps[j] += p;
            }
#pragma unroll
        for (int j = 0; j < 4; ++j) {
            ps[j] += __shfl_xor(ps[j], 1);
            ps[j] += __shfl_xor(ps[j], 2);
            ps[j] += __shfl_xor(ps[j], 4);
            ps[j] += __shfl_xor(ps[j], 8);
            l_run[j] = l_run[j] * scl[j] + ps[j];
        }
        // P (bf16) -> LDS in A-operand layout source
#pragma unroll
        for (int c = 0; c < 4; ++c)
#pragma unroll
            for (int j = 0; j < 4; ++j)
                Ps[w][(lane >> 4) * 4 + j][c * 16 + (lane & 15)] = (short)f2b(sc[c][j]);
        // rescale O
#pragma unroll
        for (int dc = 0; dc < 4; ++dc)
#pragma unroll
            for (int j = 0; j < 4; ++j) o[dc][j] *= scl[j];
        // PV
        short8 pa0 = *(const short8*)&Ps[w][(lane & 15)][(lane >> 4) * 8];
        short8 pa1 = *(const short8*)&Ps[w][(lane & 15)][32 + (lane >> 4) * 8];
#pragma unroll
        for (int dc = 0; dc < 4; ++dc) {
            short8 vf0 = *(const short8*)&Vt[dc * 16 + (lane & 15)][(lane >> 4) * 8];
            short8 vf1 = *(const short8*)&Vt[dc * 16 + (lane & 15)][32 + (lane >> 4) * 8];
            o[dc] = __builtin_amdgcn_mfma_f32_16x16x32_bf16(pa0, vf0, o[dc], 0, 0, 0);
            o[dc] = __builtin_amdgcn_mfma_f32_16x16x32_bf16(pa1, vf1, o[dc], 0, 0, 0);
        }
    }

    // write att [B,S,E] bf16
    const int b = bh >> 4, h = bh & 15;
    float inv[4];
#pragma unroll
    for (int j = 0; j < 4; ++j) inv[j] = 1.f / l_run[j];
#pragma unroll
    for (int dc = 0; dc < 4; ++dc)
#pragma unroll
        for (int j = 0; j < 4; ++j) {
            int srow = q0 + w * 16 + (lane >> 4) * 4 + j;
            int d = h * HDIM + dc * 16 + (lane & 15);
            att[((size_t)b * SEQ + srow) * EMBED + d] = f2b(o[dc][j] * inv[j]);
        }
}

// ---------------------------------------------------------------------------
extern "C" void kernel_launch(void* const* d_in, const int* in_sizes, int n_in,
                              void* d_out, int out_size, void* d_ws, size_t ws_size,
                              hipStream_t stream) {
    const float* x  = (const float*)d_in[0];
    const float* Wq = (const float*)d_in[1];
    const float* Wk = (const float*)d_in[2];
    const float* Wv = (const float*)d_in[3];
    const float* Wo = (const float*)d_in[4];
    const float* bo = (const float*)d_in[5];

    const size_t XN = (size_t)BATCH * SEQ * EMBED;  // 8388608
    const size_t WN = (size_t)EMBED * EMBED;        // 1048576

    unsigned short* ws  = (unsigned short*)d_ws;
    unsigned short* xb  = ws;
    unsigned short* wqb = xb + XN;
    unsigned short* wkb = wqb + WN;
    unsigned short* wvb = wkb + WN;
    unsigned short* wob = wvb + WN;
    unsigned short* Qb  = wob + WN;   // [B,H,S,D]
    unsigned short* Kb  = Qb + XN;
    unsigned short* Vb  = Kb + XN;
    unsigned short* attb = Vb + XN;   // [B,S,E]

    cast_bf16<<<(int)(XN / 2048), 256, 0, stream>>>(x, xb, (int)XN);
    cast_bf16<<<(int)(WN / 2048), 256, 0, stream>>>(Wq, wqb, (int)WN);
    cast_bf16<<<(int)(WN / 2048), 256, 0, stream>>>(Wk, wkb, (int)WN);
    cast_bf16<<<(int)(WN / 2048), 256, 0, stream>>>(Wv, wvb, (int)WN);
    cast_bf16<<<(int)(WN / 2048), 256, 0, stream>>>(Wo, wob, (int)WN);

    dim3 gg(EMBED / 128, BATCH * SEQ / 128);  // (8, 64)
    gemm_bf16<0><<<gg, 256, 0, stream>>>(xb, wqb, Qb, nullptr, 0.125f);  // Q * 1/sqrt(D)
    gemm_bf16<0><<<gg, 256, 0, stream>>>(xb, wkb, Kb, nullptr, 1.0f);
    gemm_bf16<0><<<gg, 256, 0, stream>>>(xb, wvb, Vb, nullptr, 1.0f);

    attn_mfma<<<dim3(SEQ / 64, BATCH * HEADS), 256, 0, stream>>>(Qb, Kb, Vb, attb);

    gemm_bf16<1><<<gg, 256, 0, stream>>>(attb, wob, d_out, bo, 1.0f);
}

// Round 3
// 363.663 us; speedup vs baseline: 8.0201x; 1.0369x over previous
//
#include <hip/hip_runtime.h>
#include <math.h>

#define EMBED 1024
#define HEADS 16
#define HDIM  64
#define SEQ   2048
#define BATCH 4
#define QBLK  128
#define KVBLK 64

typedef __attribute__((ext_vector_type(8))) short short8;
typedef __attribute__((ext_vector_type(4))) float f32x4;

__device__ __forceinline__ unsigned short f2b(float f) {
    union { float f; unsigned int u; } c; c.f = f;
    unsigned int r = (c.u + 0x7fffu + ((c.u >> 16) & 1u)) >> 16;
    return (unsigned short)r;
}

__device__ __forceinline__ void gld16(const void* g, void* l) {
    __builtin_amdgcn_global_load_lds((__attribute__((address_space(1))) void*)g,
                                     (__attribute__((address_space(3))) void*)l,
                                     16, 0, 0);
}

// fp32 -> bf16 (RNE), 8 elems/thread
__global__ __launch_bounds__(256) void cast_bf16(const float* __restrict__ src,
                                                 unsigned short* __restrict__ dst,
                                                 int n) {
    int i = (blockIdx.x * 256 + threadIdx.x) * 8;
    if (i >= n) return;
    float4 a = *(const float4*)(src + i);
    float4 b = *(const float4*)(src + i + 4);
    short8 v;
    v[0] = (short)f2b(a.x); v[1] = (short)f2b(a.y);
    v[2] = (short)f2b(a.z); v[3] = (short)f2b(a.w);
    v[4] = (short)f2b(b.x); v[5] = (short)f2b(b.y);
    v[6] = (short)f2b(b.z); v[7] = (short)f2b(b.w);
    *(short8*)(dst + i) = v;
}

// ---------------------------------------------------------------------------
// bf16 MFMA GEMM (NT): out = A @ W^T, A [M,K], W [N,K], both row-major bf16.
// 128x128 tile, BK=32, 4 waves (2x2 of 64x64), 16x16x32 MFMA, fp32 acc.
// MODE 0: scatter bf16 to [B,H,S,D], scaled by oscale.  MODE 1: fp32 [M,N]+bias.
// ---------------------------------------------------------------------------
template <int MODE>
__global__ __launch_bounds__(256) void gemm_bf16(const unsigned short* __restrict__ A,
                                                 const unsigned short* __restrict__ W,
                                                 void* __restrict__ outp,
                                                 const float* __restrict__ bias,
                                                 float oscale) {
    const int N_ = EMBED, K_ = EMBED;
    __shared__ __attribute__((aligned(16))) unsigned short As[128 * 32];
    __shared__ __attribute__((aligned(16))) unsigned short Bs[128 * 32];

    const int tid  = threadIdx.x;
    const int lane = tid & 63;
    const int w    = tid >> 6;
    const int wr   = w >> 1, wc = w & 1;
    const int m0 = blockIdx.y * 128, n0 = blockIdx.x * 128;

    const unsigned short* gA = A + (size_t)(m0 + w * 32 + (lane >> 2)) * K_ + (lane & 3) * 8;
    const unsigned short* gB = W + (size_t)(n0 + w * 32 + (lane >> 2)) * K_ + (lane & 3) * 8;
    unsigned short* lA = As + (w * 32) * 32;  // wave-uniform LDS base
    unsigned short* lB = Bs + (w * 32) * 32;

    f32x4 zero = {0.f, 0.f, 0.f, 0.f};
    f32x4 acc[4][4];
#pragma unroll
    for (int i = 0; i < 4; ++i)
#pragma unroll
        for (int j = 0; j < 4; ++j) acc[i][j] = zero;

    for (int k0 = 0; k0 < K_; k0 += 32) {
        gld16(gA, lA);
        gld16(gA + (size_t)16 * K_, lA + 16 * 32);
        gld16(gB, lB);
        gld16(gB + (size_t)16 * K_, lB + 16 * 32);
        gA += 32; gB += 32;
        __syncthreads();
        short8 af[4], bfr[4];
#pragma unroll
        for (int i = 0; i < 4; ++i) {
            af[i]  = *(const short8*)&As[(wr * 64 + i * 16 + (lane & 15)) * 32 + (lane >> 4) * 8];
            bfr[i] = *(const short8*)&Bs[(wc * 64 + i * 16 + (lane & 15)) * 32 + (lane >> 4) * 8];
        }
#pragma unroll
        for (int i = 0; i < 4; ++i)
#pragma unroll
            for (int j = 0; j < 4; ++j)
                acc[i][j] = __builtin_amdgcn_mfma_f32_16x16x32_bf16(af[i], bfr[j], acc[i][j], 0, 0, 0);
        __syncthreads();
    }

    if (MODE == 0) {
        unsigned short* dst = (unsigned short*)outp;
#pragma unroll
        for (int i = 0; i < 4; ++i)
#pragma unroll
            for (int ni = 0; ni < 4; ++ni) {
                int n = n0 + wc * 64 + ni * 16 + (lane & 15);
                int h = n >> 6, d = n & 63;
#pragma unroll
                for (int j = 0; j < 4; ++j) {
                    int m = m0 + wr * 64 + i * 16 + (lane >> 4) * 4 + j;
                    int b = m >> 11, s = m & (SEQ - 1);
                    dst[(((size_t)b * HEADS + h) * SEQ + s) * HDIM + d] =
                        f2b(acc[i][ni][j] * oscale);
                }
            }
    } else {
        float* dst = (float*)outp;
#pragma unroll
        for (int i = 0; i < 4; ++i)
#pragma unroll
            for (int ni = 0; ni < 4; ++ni) {
                int n = n0 + wc * 64 + ni * 16 + (lane & 15);
                float bv = bias[n];
#pragma unroll
                for (int j = 0; j < 4; ++j) {
                    int m = m0 + wr * 64 + i * 16 + (lane >> 4) * 4 + j;
                    dst[(size_t)m * EMBED + n] = acc[i][ni][j] + bv;
                }
            }
    }
}

// ---------------------------------------------------------------------------
// MFMA flash attention (causal). Q pre-scaled by 1/sqrt(D).
// Block = 4 waves; wave owns 32 q-rows (QBLK=128). KV tile = 64.
// Pipelined: next tile's K/V global loads issued before compute (T14),
// written to LDS after the barrier. K double-buffered, V single (2 barriers).
// ---------------------------------------------------------------------------
__global__ __launch_bounds__(256) void attn_mfma(const unsigned short* __restrict__ Q,
                                                 const unsigned short* __restrict__ K,
                                                 const unsigned short* __restrict__ V,
                                                 unsigned short* __restrict__ att) {
    __shared__ __attribute__((aligned(16))) short Ks[2][64][72];  // 18432 B
    __shared__ __attribute__((aligned(16))) short Vt[64][72];     //  9216 B
    __shared__ __attribute__((aligned(16))) short Ps[4][32][72];  // 18432 B

    const int tid  = threadIdx.x;
    const int lane = tid & 63;
    const int w    = tid >> 6;
    const int qt   = (SEQ / QBLK - 1) - blockIdx.x;  // heavy blocks first
    const int bh   = blockIdx.y;
    const int q0   = qt * QBLK;
    const size_t base = (size_t)bh * SEQ * HDIM;

    // K staging: thread t -> row r = t>>2, octets (t&3), (t&3)+4
    const int kr = tid >> 2, ko = tid & 3;
    // V staging: thread t -> row pair rp = t&31 (rows 2rp,2rp+1), d-octet dg = t>>5
    const int vrp = tid & 31, vdg = tid >> 5;

    // Q fragments: rows q0 + w*32 + rb*16 + (lane&15), k-octet lane>>4 (+kk*32)
    const unsigned short* qp =
        Q + base + (size_t)(q0 + w * 32 + (lane & 15)) * HDIM + (lane >> 4) * 8;
    short8 qf00 = *(const short8*)qp;
    short8 qf01 = *(const short8*)(qp + 32);
    short8 qf10 = *(const short8*)(qp + 16 * HDIM);
    short8 qf11 = *(const short8*)(qp + 16 * HDIM + 32);

    f32x4 zero = {0.f, 0.f, 0.f, 0.f};
    f32x4 o[2][4];
    float m_run[2][4], l_run[2][4];
#pragma unroll
    for (int rb = 0; rb < 2; ++rb)
#pragma unroll
        for (int i = 0; i < 4; ++i) {
            o[rb][i] = zero; m_run[rb][i] = -INFINITY; l_run[rb][i] = 0.f;
        }

    const int rowmin = q0 + w * 32;       // wave's first q-row
    const int ntiles = 2 * qt + 2;

    // ---- prologue: stage tile 0 ----
    {
        const unsigned short* kp = K + base + (size_t)kr * HDIM;
        short8 ka = *(const short8*)(kp + ko * 8);
        short8 kb = *(const short8*)(kp + (ko + 4) * 8);
        const unsigned short* vp = V + base + (size_t)(2 * vrp) * HDIM + vdg * 8;
        short8 va = *(const short8*)vp;
        short8 vb = *(const short8*)(vp + HDIM);
        *(short8*)&Ks[0][kr][ko * 8] = ka;
        *(short8*)&Ks[0][kr][(ko + 4) * 8] = kb;
#pragma unroll
        for (int e = 0; e < 8; ++e) {
            unsigned int pk = (unsigned int)(unsigned short)va[e] |
                              ((unsigned int)(unsigned short)vb[e] << 16);
            *(unsigned int*)&Vt[vdg * 8 + e][2 * vrp] = pk;
        }
    }
    __syncthreads();

    for (int kt = 0; kt < ntiles; ++kt) {
        const int cur = kt & 1;
        const int k0 = kt * KVBLK;
        const bool pf = (kt + 1 < ntiles);

        // ---- issue next tile's global loads (latency hides under compute) ----
        short8 ka, kb, va, vb;
        if (pf) {
            const int k0n = k0 + KVBLK;
            const unsigned short* kp = K + base + (size_t)(k0n + kr) * HDIM;
            ka = *(const short8*)(kp + ko * 8);
            kb = *(const short8*)(kp + (ko + 4) * 8);
            const unsigned short* vp = V + base + (size_t)(k0n + 2 * vrp) * HDIM + vdg * 8;
            va = *(const short8*)vp;
            vb = *(const short8*)(vp + HDIM);
        }

        // ---- compute tile kt ----
        if (k0 <= rowmin + 31) {
            f32x4 sc[2][4];
#pragma unroll
            for (int c = 0; c < 4; ++c) {
                short8 kf0 = *(const short8*)&Ks[cur][c * 16 + (lane & 15)][(lane >> 4) * 8];
                short8 kf1 = *(const short8*)&Ks[cur][c * 16 + (lane & 15)][32 + (lane >> 4) * 8];
                sc[0][c] = __builtin_amdgcn_mfma_f32_16x16x32_bf16(qf00, kf0, zero, 0, 0, 0);
                sc[0][c] = __builtin_amdgcn_mfma_f32_16x16x32_bf16(qf01, kf1, sc[0][c], 0, 0, 0);
                sc[1][c] = __builtin_amdgcn_mfma_f32_16x16x32_bf16(qf10, kf0, zero, 0, 0, 0);
                sc[1][c] = __builtin_amdgcn_mfma_f32_16x16x32_bf16(qf11, kf1, sc[1][c], 0, 0, 0);
            }

            if (k0 + 63 > rowmin) {  // causal mask on overlapping tiles
#pragma unroll
                for (int rb = 0; rb < 2; ++rb)
#pragma unroll
                    for (int c = 0; c < 4; ++c)
#pragma unroll
                        for (int j = 0; j < 4; ++j) {
                            int row = rowmin + rb * 16 + (lane >> 4) * 4 + j;
                            int col = k0 + c * 16 + (lane & 15);
                            if (col > row) sc[rb][c][j] = -INFINITY;
                        }
            }

            float scl[2][4];
#pragma unroll
            for (int rb = 0; rb < 2; ++rb)
#pragma unroll
                for (int j = 0; j < 4; ++j) {
                    float mx = fmaxf(fmaxf(sc[rb][0][j], sc[rb][1][j]),
                                     fmaxf(sc[rb][2][j], sc[rb][3][j]));
                    mx = fmaxf(mx, __shfl_xor(mx, 1));
                    mx = fmaxf(mx, __shfl_xor(mx, 2));
                    mx = fmaxf(mx, __shfl_xor(mx, 4));
                    mx = fmaxf(mx, __shfl_xor(mx, 8));
                    float mnew = fmaxf(m_run[rb][j], mx);
                    scl[rb][j] = __expf(m_run[rb][j] - mnew);
                    m_run[rb][j] = mnew;
                    float ps = 0.f;
#pragma unroll
                    for (int c = 0; c < 4; ++c) {
                        float p = __expf(sc[rb][c][j] - mnew);
                        sc[rb][c][j] = p;
                        ps += p;
                    }
                    ps += __shfl_xor(ps, 1);
                    ps += __shfl_xor(ps, 2);
                    ps += __shfl_xor(ps, 4);
                    ps += __shfl_xor(ps, 8);
                    l_run[rb][j] = l_run[rb][j] * scl[rb][j] + ps;
                }

            // P -> LDS (A-operand source layout)
#pragma unroll
            for (int rb = 0; rb < 2; ++rb)
#pragma unroll
                for (int c = 0; c < 4; ++c)
#pragma unroll
                    for (int j = 0; j < 4; ++j)
                        Ps[w][rb * 16 + (lane >> 4) * 4 + j][c * 16 + (lane & 15)] =
                            (short)f2b(sc[rb][c][j]);

            // rescale O
#pragma unroll
            for (int rb = 0; rb < 2; ++rb)
#pragma unroll
                for (int dc = 0; dc < 4; ++dc)
#pragma unroll
                    for (int j = 0; j < 4; ++j) o[rb][dc][j] *= scl[rb][j];

            short8 pa00 = *(const short8*)&Ps[w][(lane & 15)][(lane >> 4) * 8];
            short8 pa01 = *(const short8*)&Ps[w][(lane & 15)][32 + (lane >> 4) * 8];
            short8 pa10 = *(const short8*)&Ps[w][16 + (lane & 15)][(lane >> 4) * 8];
            short8 pa11 = *(const short8*)&Ps[w][16 + (lane & 15)][32 + (lane >> 4) * 8];
#pragma unroll
            for (int dc = 0; dc < 4; ++dc) {
                short8 vf0 = *(const short8*)&Vt[dc * 16 + (lane & 15)][(lane >> 4) * 8];
                short8 vf1 = *(const short8*)&Vt[dc * 16 + (lane & 15)][32 + (lane >> 4) * 8];
                o[0][dc] = __builtin_amdgcn_mfma_f32_16x16x32_bf16(pa00, vf0, o[0][dc], 0, 0, 0);
                o[0][dc] = __builtin_amdgcn_mfma_f32_16x16x32_bf16(pa01, vf1, o[0][dc], 0, 0, 0);
                o[1][dc] = __builtin_amdgcn_mfma_f32_16x16x32_bf16(pa10, vf0, o[1][dc], 0, 0, 0);
                o[1][dc] = __builtin_amdgcn_mfma_f32_16x16x32_bf16(pa11, vf1, o[1][dc], 0, 0, 0);
            }
        }

        // write prefetched K (other buffer — safe before barrier)
        if (pf) {
            *(short8*)&Ks[1 - cur][kr][ko * 8] = ka;
            *(short8*)&Ks[1 - cur][kr][(ko + 4) * 8] = kb;
        }
        __syncthreads();  // all PV reads of Vt done; K[1-cur] writes landed
        if (pf) {
#pragma unroll
            for (int e = 0; e < 8; ++e) {
                unsigned int pk = (unsigned int)(unsigned short)va[e] |
                                  ((unsigned int)(unsigned short)vb[e] << 16);
                *(unsigned int*)&Vt[vdg * 8 + e][2 * vrp] = pk;
            }
            __syncthreads();  // Vt ready for next iter
        }
    }

    // epilogue: write att [B,S,E] bf16
    const int b = bh >> 4, h = bh & 15;
#pragma unroll
    for (int rb = 0; rb < 2; ++rb) {
        float inv[4];
#pragma unroll
        for (int j = 0; j < 4; ++j) inv[j] = 1.f / l_run[rb][j];
#pragma unroll
        for (int dc = 0; dc < 4; ++dc)
#pragma unroll
            for (int j = 0; j < 4; ++j) {
                int srow = q0 + w * 32 + rb * 16 + (lane >> 4) * 4 + j;
                int d = h * HDIM + dc * 16 + (lane & 15);
                att[((size_t)b * SEQ + srow) * EMBED + d] = f2b(o[rb][dc][j] * inv[j]);
            }
    }
}

// ---------------------------------------------------------------------------
extern "C" void kernel_launch(void* const* d_in, const int* in_sizes, int n_in,
                              void* d_out, int out_size, void* d_ws, size_t ws_size,
                              hipStream_t stream) {
    const float* x  = (const float*)d_in[0];
    const float* Wq = (const float*)d_in[1];
    const float* Wk = (const float*)d_in[2];
    const float* Wv = (const float*)d_in[3];
    const float* Wo = (const float*)d_in[4];
    const float* bo = (const float*)d_in[5];

    const size_t XN = (size_t)BATCH * SEQ * EMBED;  // 8388608
    const size_t WN = (size_t)EMBED * EMBED;        // 1048576

    unsigned short* ws  = (unsigned short*)d_ws;
    unsigned short* xb  = ws;
    unsigned short* wqb = xb + XN;
    unsigned short* wkb = wqb + WN;
    unsigned short* wvb = wkb + WN;
    unsigned short* wob = wvb + WN;
    unsigned short* Qb  = wob + WN;   // [B,H,S,D]
    unsigned short* Kb  = Qb + XN;
    unsigned short* Vb  = Kb + XN;
    unsigned short* attb = Vb + XN;   // [B,S,E]

    cast_bf16<<<(int)(XN / 2048), 256, 0, stream>>>(x, xb, (int)XN);
    cast_bf16<<<(int)(WN / 2048), 256, 0, stream>>>(Wq, wqb, (int)WN);
    cast_bf16<<<(int)(WN / 2048), 256, 0, stream>>>(Wk, wkb, (int)WN);
    cast_bf16<<<(int)(WN / 2048), 256, 0, stream>>>(Wv, wvb, (int)WN);
    cast_bf16<<<(int)(WN / 2048), 256, 0, stream>>>(Wo, wob, (int)WN);

    dim3 gg(EMBED / 128, BATCH * SEQ / 128);  // (8, 64)
    gemm_bf16<0><<<gg, 256, 0, stream>>>(xb, wqb, Qb, nullptr, 0.125f);  // Q * 1/sqrt(D)
    gemm_bf16<0><<<gg, 256, 0, stream>>>(xb, wkb, Kb, nullptr, 1.0f);
    gemm_bf16<0><<<gg, 256, 0, stream>>>(xb, wvb, Vb, nullptr, 1.0f);

    attn_mfma<<<dim3(SEQ / QBLK, BATCH * HEADS), 256, 0, stream>>>(Qb, Kb, Vb, attb);

    gemm_bf16<1><<<gg, 256, 0, stream>>>(attb, wob, d_out, bo, 1.0f);
}

// Round 4
// 279.143 us; speedup vs baseline: 10.4484x; 1.3028x over previous
//
#include <hip/hip_runtime.h>
#include <math.h>

#define EMBED 1024
#define HEADS 16
#define HDIM  64
#define SEQ   2048
#define BATCH 4
#define QBLK  128
#define KVBLK 64
// 1/sqrt(64) * log2(e)  (softmax done in exp2 domain)
#define QSCALE 0.18033688011112042f

typedef __attribute__((ext_vector_type(8))) short short8;
typedef __attribute__((ext_vector_type(4))) float f32x4;
typedef __attribute__((ext_vector_type(16))) float f32x16;
typedef __attribute__((ext_vector_type(2))) unsigned int uint2v;

__device__ __forceinline__ unsigned short f2b(float f) {
    union { float f; unsigned int u; } c; c.f = f;
    unsigned int r = (c.u + 0x7fffu + ((c.u >> 16) & 1u)) >> 16;
    return (unsigned short)r;
}

__device__ __forceinline__ unsigned int cvtpk(float lo, float hi) {
    unsigned int r;
    asm("v_cvt_pk_bf16_f32 %0, %1, %2" : "=v"(r) : "v"(lo), "v"(hi));
    return r;
}

__device__ __forceinline__ void gld16(const void* g, void* l) {
    __builtin_amdgcn_global_load_lds((__attribute__((address_space(1))) void*)g,
                                     (__attribute__((address_space(3))) void*)l,
                                     16, 0, 0);
}

__device__ __forceinline__ f32x16 zero16() {
    f32x16 z;
#pragma unroll
    for (int i = 0; i < 16; ++i) z[i] = 0.f;
    return z;
}

// P (f32, C-layout of S^T) -> two B-operand fragments (keys 0-15, 16-31 rel).
__device__ __forceinline__ void makePB(const f32x16 s, short8& f0, short8& f1) {
    union { unsigned int u[4]; short8 s8; } t;
    {
        unsigned int A0 = cvtpk(s[0], s[1]), A1 = cvtpk(s[2], s[3]);
        unsigned int B0 = cvtpk(s[4], s[5]), B1 = cvtpk(s[6], s[7]);
        uint2v w0 = __builtin_amdgcn_permlane32_swap(A0, B0, false, false);
        uint2v w1 = __builtin_amdgcn_permlane32_swap(A1, B1, false, false);
        t.u[0] = w0[0]; t.u[1] = w1[0]; t.u[2] = w0[1]; t.u[3] = w1[1];
        f0 = t.s8;
    }
    {
        unsigned int A0 = cvtpk(s[8], s[9]), A1 = cvtpk(s[10], s[11]);
        unsigned int B0 = cvtpk(s[12], s[13]), B1 = cvtpk(s[14], s[15]);
        uint2v w0 = __builtin_amdgcn_permlane32_swap(A0, B0, false, false);
        uint2v w1 = __builtin_amdgcn_permlane32_swap(A1, B1, false, false);
        t.u[0] = w0[0]; t.u[1] = w1[0]; t.u[2] = w0[1]; t.u[3] = w1[1];
        f1 = t.s8;
    }
}

// fp32 -> bf16 (RNE), 8 elems/thread
__global__ __launch_bounds__(256) void cast_bf16(const float* __restrict__ src,
                                                 unsigned short* __restrict__ dst,
                                                 int n) {
    int i = (blockIdx.x * 256 + threadIdx.x) * 8;
    if (i >= n) return;
    float4 a = *(const float4*)(src + i);
    float4 b = *(const float4*)(src + i + 4);
    short8 v;
    v[0] = (short)f2b(a.x); v[1] = (short)f2b(a.y);
    v[2] = (short)f2b(a.z); v[3] = (short)f2b(a.w);
    v[4] = (short)f2b(b.x); v[5] = (short)f2b(b.y);
    v[6] = (short)f2b(b.z); v[7] = (short)f2b(b.w);
    *(short8*)(dst + i) = v;
}

// ---------------------------------------------------------------------------
// bf16 MFMA GEMM (NT): out = A @ W^T. 128x128 tile, BK=32, 4 waves.
// MODE 0: fused QKV, W = [Wq;Wk;Wv] (N=3072); scatter bf16 to [3][B,H,S,D];
//         Q part scaled by QSCALE.
// MODE 1: N=1024, fp32 out [M,N] + bias.
// ---------------------------------------------------------------------------
template <int MODE>
__global__ __launch_bounds__(256) void gemm_bf16(const unsigned short* __restrict__ A,
                                                 const unsigned short* __restrict__ W,
                                                 void* __restrict__ outp,
                                                 const float* __restrict__ bias) {
    const int K_ = EMBED;
    __shared__ __attribute__((aligned(16))) unsigned short As[128 * 32];
    __shared__ __attribute__((aligned(16))) unsigned short Bs[128 * 32];

    const int tid  = threadIdx.x;
    const int lane = tid & 63;
    const int w    = tid >> 6;
    const int wr   = w >> 1, wc = w & 1;
    const int m0 = blockIdx.y * 128, n0 = blockIdx.x * 128;

    const unsigned short* gA = A + (size_t)(m0 + w * 32 + (lane >> 2)) * K_ + (lane & 3) * 8;
    const unsigned short* gB = W + (size_t)(n0 + w * 32 + (lane >> 2)) * K_ + (lane & 3) * 8;
    unsigned short* lA = As + (w * 32) * 32;
    unsigned short* lB = Bs + (w * 32) * 32;

    f32x4 zero = {0.f, 0.f, 0.f, 0.f};
    f32x4 acc[4][4];
#pragma unroll
    for (int i = 0; i < 4; ++i)
#pragma unroll
        for (int j = 0; j < 4; ++j) acc[i][j] = zero;

    for (int k0 = 0; k0 < K_; k0 += 32) {
        gld16(gA, lA);
        gld16(gA + (size_t)16 * K_, lA + 16 * 32);
        gld16(gB, lB);
        gld16(gB + (size_t)16 * K_, lB + 16 * 32);
        gA += 32; gB += 32;
        __syncthreads();
        short8 af[4], bfr[4];
#pragma unroll
        for (int i = 0; i < 4; ++i) {
            af[i]  = *(const short8*)&As[(wr * 64 + i * 16 + (lane & 15)) * 32 + (lane >> 4) * 8];
            bfr[i] = *(const short8*)&Bs[(wc * 64 + i * 16 + (lane & 15)) * 32 + (lane >> 4) * 8];
        }
#pragma unroll
        for (int i = 0; i < 4; ++i)
#pragma unroll
            for (int j = 0; j < 4; ++j)
                acc[i][j] = __builtin_amdgcn_mfma_f32_16x16x32_bf16(af[i], bfr[j], acc[i][j], 0, 0, 0);
        __syncthreads();
    }

    if (MODE == 0) {
        const size_t PP = (size_t)BATCH * SEQ * EMBED;  // per-tensor elems
        unsigned short* dst = (unsigned short*)outp;
#pragma unroll
        for (int i = 0; i < 4; ++i)
#pragma unroll
            for (int ni = 0; ni < 4; ++ni) {
                int n = n0 + wc * 64 + ni * 16 + (lane & 15);
                int which = n >> 10;            // 0=Q 1=K 2=V (uniform per block)
                int h = (n >> 6) & 15, d = n & 63;
                float os = (which == 0) ? QSCALE : 1.0f;
#pragma unroll
                for (int j = 0; j < 4; ++j) {
                    int m = m0 + wr * 64 + i * 16 + (lane >> 4) * 4 + j;
                    int b = m >> 11, s = m & (SEQ - 1);
                    dst[(size_t)which * PP + (((size_t)b * HEADS + h) * SEQ + s) * HDIM + d] =
                        f2b(acc[i][ni][j] * os);
                }
            }
    } else {
        float* dst = (float*)outp;
#pragma unroll
        for (int i = 0; i < 4; ++i)
#pragma unroll
            for (int ni = 0; ni < 4; ++ni) {
                int n = n0 + wc * 64 + ni * 16 + (lane & 15);
                float bv = bias[n];
#pragma unroll
                for (int j = 0; j < 4; ++j) {
                    int m = m0 + wr * 64 + i * 16 + (lane >> 4) * 4 + j;
                    dst[(size_t)m * EMBED + n] = acc[i][ni][j] + bv;
                }
            }
    }
}

// ---------------------------------------------------------------------------
// Flash attention, 32x32 swapped-QK structure (m214 style).
// 4 waves x 32 q-rows (QBLK=128), KV tile 64, K/Vt double-buffered in LDS
// (XOR-swizzled), softmax fully in-register, P->PV via cvt_pk+permlane32_swap.
// Scores are in exp2 domain (Q pre-scaled by 1/sqrt(D)*log2e).
// ---------------------------------------------------------------------------
__global__ __launch_bounds__(256) void attn_mfma32(const unsigned short* __restrict__ Q,
                                                   const unsigned short* __restrict__ K,
                                                   const unsigned short* __restrict__ V,
                                                   unsigned short* __restrict__ att) {
    __shared__ __attribute__((aligned(16))) unsigned short KsL[2][64 * 64];  // [key][d] swz
    __shared__ __attribute__((aligned(16))) unsigned short VtL[2][64 * 64];  // [d][key] swz

    const int tid  = threadIdx.x;
    const int lane = tid & 63;
    const int wv   = tid >> 6;
    const int hi   = lane >> 5;
    const int lq   = lane & 31;
    const int qt   = (SEQ / QBLK - 1) - blockIdx.x;  // heavy blocks first
    const int bh   = blockIdx.y;
    const int q0   = qt * QBLK;
    const int q0w  = q0 + wv * 32;
    const size_t base = (size_t)bh * SEQ * HDIM;

    // Q B-operand frags: col q = lq, k(d) = dc*16 + hi*8 + e
    const unsigned short* qrow = Q + base + (size_t)(q0w + lq) * HDIM + hi * 8;
    short8 qf[4];
    qf[0] = *(const short8*)(qrow);
    qf[1] = *(const short8*)(qrow + 16);
    qf[2] = *(const short8*)(qrow + 32);
    qf[3] = *(const short8*)(qrow + 48);

    // K staging (global_load_lds, pre-swizzled global source)
    const int krow = tid >> 3, kslot = tid & 7;
    const int kxor = (kslot ^ (krow & 7)) * 8;  // element offset in row

    // V staging (reg->LDS transposed, swizzled packed writes)
    const int vrp = tid & 31, vdg = tid >> 5;
    const unsigned short* vptr = V + base + (size_t)(2 * vrp) * HDIM + vdg * 8;

    f32x16 o0 = zero16(), o1 = zero16();
    float m_run = -INFINITY, l_run = 0.f;
    const int qsel = q0w + lq;
    const int ntiles = 2 * qt + 2;

    // ---- prologue: stage tile 0 ----
    {
        const unsigned short* g0 = K + base + (size_t)krow * HDIM + kxor;
        unsigned short* l0 = &KsL[0][wv * 512];
        gld16(g0, l0);
        gld16(g0 + 32 * HDIM, l0 + 2048);
        short8 va = *(const short8*)vptr;
        short8 vb = *(const short8*)(vptr + HDIM);
        char* vbase = (char*)&VtL[0][0];
#pragma unroll
        for (int e = 0; e < 8; ++e) {
            unsigned int pk = (unsigned int)(unsigned short)va[e] |
                              ((unsigned int)(unsigned short)vb[e] << 16);
            *(unsigned int*)(vbase + ((vdg * 8 + e) << 7) + ((4 * vrp) ^ (e << 4))) = pk;
        }
    }
    __syncthreads();

    for (int kt = 0; kt < ntiles; ++kt) {
        const int buf = kt & 1, nbuf = buf ^ 1;
        const int k0 = kt * KVBLK;
        const bool pf = (kt + 1 < ntiles);

        short8 va, vb;
        if (pf) {  // issue next tile's loads early (T14)
            const int k0n = k0 + KVBLK;
            const unsigned short* g0 = K + base + (size_t)(k0n + krow) * HDIM + kxor;
            unsigned short* l0 = &KsL[nbuf][wv * 512];
            gld16(g0, l0);
            gld16(g0 + 32 * HDIM, l0 + 2048);
            const unsigned short* vp = vptr + (size_t)k0n * HDIM;
            va = *(const short8*)vp;
            vb = *(const short8*)(vp + HDIM);
        }

        if (k0 <= q0w + 31) {  // wave-active tile
            const bool kb1 = (k0 + 32 <= q0w + 31);
            const char* kbase = (const char*)&KsL[buf][0];
            const int ksw = (lane & 7) << 4;

            // ---- QK^T (S^T = K x Q) ----
            f32x16 s0 = zero16(), s1 = zero16();
            __builtin_amdgcn_s_setprio(1);
#pragma unroll
            for (int dc = 0; dc < 4; ++dc) {
                short8 kf = *(const short8*)(kbase + (lq << 7) + ((((dc << 1) | hi) << 4) ^ ksw));
                s0 = __builtin_amdgcn_mfma_f32_32x32x16_bf16(kf, qf[dc], s0, 0, 0, 0);
            }
            if (kb1) {
#pragma unroll
                for (int dc = 0; dc < 4; ++dc) {
                    short8 kf = *(const short8*)(kbase + ((32 + lq) << 7) + ((((dc << 1) | hi) << 4) ^ ksw));
                    s1 = __builtin_amdgcn_mfma_f32_32x32x16_bf16(kf, qf[dc], s1, 0, 0, 0);
                }
            }
            __builtin_amdgcn_s_setprio(0);

            // ---- causal mask (reg r -> key = k0 + kb*32 + (r&3)+8*(r>>2)+4*hi) ----
            if (k0 + 31 > q0w) {
#pragma unroll
                for (int r = 0; r < 16; ++r) {
                    int key = k0 + (r & 3) + 8 * (r >> 2) + 4 * hi;
                    if (key > qsel) s0[r] = -INFINITY;
                }
            }
            if (kb1 && (k0 + 63 > q0w)) {
#pragma unroll
                for (int r = 0; r < 16; ++r) {
                    int key = k0 + 32 + (r & 3) + 8 * (r >> 2) + 4 * hi;
                    if (key > qsel) s1[r] = -INFINITY;
                }
            }

            // ---- online softmax, fully per-lane (one q per lane) ----
            float mx = s0[0];
#pragma unroll
            for (int r = 1; r < 16; ++r) mx = fmaxf(mx, s0[r]);
            if (kb1) {
#pragma unroll
                for (int r = 0; r < 16; ++r) mx = fmaxf(mx, s1[r]);
            }
            mx = fmaxf(mx, __shfl_xor(mx, 32));
            const float mnew = fmaxf(m_run, mx);
            const float scl = __builtin_exp2f(m_run - mnew);
            m_run = mnew;
            float ps = 0.f;
#pragma unroll
            for (int r = 0; r < 16; ++r) {
                float p = __builtin_exp2f(s0[r] - mnew);
                s0[r] = p; ps += p;
            }
            if (kb1) {
#pragma unroll
                for (int r = 0; r < 16; ++r) {
                    float p = __builtin_exp2f(s1[r] - mnew);
                    s1[r] = p; ps += p;
                }
            }
            ps += __shfl_xor(ps, 32);
            l_run = l_run * scl + ps;
#pragma unroll
            for (int r = 0; r < 16; ++r) { o0[r] *= scl; o1[r] *= scl; }

            // ---- P -> B-operand frags (in-register, T12) ----
            short8 pb00, pb01, pb10, pb11;
            makePB(s0, pb00, pb01);
            if (kb1) makePB(s1, pb10, pb11);

            // ---- PV (O^T += V^T x P^T) ----
            const char* vtb = (const char*)&VtL[buf][0];
            __builtin_amdgcn_s_setprio(1);
            {
                short8 vf;
                vf = *(const short8*)(vtb + (lq << 7) + ((0 + hi * 16) ^ ksw));
                o0 = __builtin_amdgcn_mfma_f32_32x32x16_bf16(vf, pb00, o0, 0, 0, 0);
                vf = *(const short8*)(vtb + (lq << 7) + ((32 + hi * 16) ^ ksw));
                o0 = __builtin_amdgcn_mfma_f32_32x32x16_bf16(vf, pb01, o0, 0, 0, 0);
                vf = *(const short8*)(vtb + ((32 + lq) << 7) + ((0 + hi * 16) ^ ksw));
                o1 = __builtin_amdgcn_mfma_f32_32x32x16_bf16(vf, pb00, o1, 0, 0, 0);
                vf = *(const short8*)(vtb + ((32 + lq) << 7) + ((32 + hi * 16) ^ ksw));
                o1 = __builtin_amdgcn_mfma_f32_32x32x16_bf16(vf, pb01, o1, 0, 0, 0);
                if (kb1) {
                    vf = *(const short8*)(vtb + (lq << 7) + ((64 + hi * 16) ^ ksw));
                    o0 = __builtin_amdgcn_mfma_f32_32x32x16_bf16(vf, pb10, o0, 0, 0, 0);
                    vf = *(const short8*)(vtb + (lq << 7) + ((96 + hi * 16) ^ ksw));
                    o0 = __builtin_amdgcn_mfma_f32_32x32x16_bf16(vf, pb11, o0, 0, 0, 0);
                    vf = *(const short8*)(vtb + ((32 + lq) << 7) + ((64 + hi * 16) ^ ksw));
                    o1 = __builtin_amdgcn_mfma_f32_32x32x16_bf16(vf, pb10, o1, 0, 0, 0);
                    vf = *(const short8*)(vtb + ((32 + lq) << 7) + ((96 + hi * 16) ^ ksw));
                    o1 = __builtin_amdgcn_mfma_f32_32x32x16_bf16(vf, pb11, o1, 0, 0, 0);
                }
            }
            __builtin_amdgcn_s_setprio(0);
        }

        // write prefetched V^T into the other buffer
        if (pf) {
            char* vbase = (char*)&VtL[nbuf][0];
#pragma unroll
            for (int e = 0; e < 8; ++e) {
                unsigned int pk = (unsigned int)(unsigned short)va[e] |
                                  ((unsigned int)(unsigned short)vb[e] << 16);
                *(unsigned int*)(vbase + ((vdg * 8 + e) << 7) + ((4 * vrp) ^ (e << 4))) = pk;
            }
        }
        __syncthreads();  // K[nbuf] landed (vmcnt drain), Vt[nbuf] visible, cur reads done
    }

    // ---- epilogue: O^T regs -> att [B,S,E] bf16 ----
    const int b = bh >> 4, h = bh & 15;
    const float invl = 1.f / l_run;
    unsigned short* orow = att + ((size_t)b * SEQ + (q0w + lq)) * EMBED + h * HDIM + 4 * hi;
#pragma unroll
    for (int c = 0; c < 4; ++c) {
        unsigned int w0 = cvtpk(o0[4 * c] * invl, o0[4 * c + 1] * invl);
        unsigned int w1 = cvtpk(o0[4 * c + 2] * invl, o0[4 * c + 3] * invl);
        *(uint2*)(orow + 8 * c) = make_uint2(w0, w1);
        unsigned int w2 = cvtpk(o1[4 * c] * invl, o1[4 * c + 1] * invl);
        unsigned int w3 = cvtpk(o1[4 * c + 2] * invl, o1[4 * c + 3] * invl);
        *(uint2*)(orow + 32 + 8 * c) = make_uint2(w2, w3);
    }
}

// ---------------------------------------------------------------------------
extern "C" void kernel_launch(void* const* d_in, const int* in_sizes, int n_in,
                              void* d_out, int out_size, void* d_ws, size_t ws_size,
                              hipStream_t stream) {
    const float* x  = (const float*)d_in[0];
    const float* Wq = (const float*)d_in[1];
    const float* Wk = (const float*)d_in[2];
    const float* Wv = (const float*)d_in[3];
    const float* Wo = (const float*)d_in[4];
    const float* bo = (const float*)d_in[5];

    const size_t XN = (size_t)BATCH * SEQ * EMBED;  // 8388608
    const size_t WN = (size_t)EMBED * EMBED;        // 1048576

    unsigned short* ws   = (unsigned short*)d_ws;
    unsigned short* xb   = ws;
    unsigned short* wqkv = xb + XN;        // [3*1024][1024]
    unsigned short* wob  = wqkv + 3 * WN;
    unsigned short* Qb   = wob + WN;       // [B,H,S,D]; Kb, Vb follow
    unsigned short* attb = Qb + 3 * XN;    // [B,S,E]

    cast_bf16<<<(int)(XN / 2048), 256, 0, stream>>>(x, xb, (int)XN);
    cast_bf16<<<(int)(WN / 2048), 256, 0, stream>>>(Wq, wqkv, (int)WN);
    cast_bf16<<<(int)(WN / 2048), 256, 0, stream>>>(Wk, wqkv + WN, (int)WN);
    cast_bf16<<<(int)(WN / 2048), 256, 0, stream>>>(Wv, wqkv + 2 * WN, (int)WN);
    cast_bf16<<<(int)(WN / 2048), 256, 0, stream>>>(Wo, wob, (int)WN);

    // fused QKV projection: [8192,1024] x [3072,1024]^T
    gemm_bf16<0><<<dim3(3 * EMBED / 128, BATCH * SEQ / 128), 256, 0, stream>>>(
        xb, wqkv, Qb, nullptr);

    attn_mfma32<<<dim3(SEQ / QBLK, BATCH * HEADS), 256, 0, stream>>>(
        Qb, Qb + XN, Qb + 2 * XN, attb);

    gemm_bf16<1><<<dim3(EMBED / 128, BATCH * SEQ / 128), 256, 0, stream>>>(
        attb, wob, d_out, bo);
}

// Round 5
// 194.897 us; speedup vs baseline: 14.9649x; 1.4323x over previous
//
#include <hip/hip_runtime.h>
#include <math.h>

#define EMBED 1024
#define HEADS 16
#define HDIM  64
#define SEQ   2048
#define BATCH 4
#define QBLK  128
#define KVBLK 128
#define NQT   (SEQ / QBLK)  // 16
// 1/sqrt(64) * log2(e)  (softmax done in exp2 domain)
#define QSCALE 0.18033688011112042f

typedef __attribute__((ext_vector_type(8))) short short8;
typedef __attribute__((ext_vector_type(4))) float f32x4;
typedef __attribute__((ext_vector_type(16))) float f32x16;
typedef __attribute__((ext_vector_type(2))) unsigned int uint2v;

__device__ __forceinline__ unsigned short f2b(float f) {
    union { float f; unsigned int u; } c; c.f = f;
    unsigned int r = (c.u + 0x7fffu + ((c.u >> 16) & 1u)) >> 16;
    return (unsigned short)r;
}

__device__ __forceinline__ unsigned int cvtpk(float lo, float hi) {
    unsigned int r;
    asm("v_cvt_pk_bf16_f32 %0, %1, %2" : "=v"(r) : "v"(lo), "v"(hi));
    return r;
}

__device__ __forceinline__ void gld16(const void* g, void* l) {
    __builtin_amdgcn_global_load_lds((__attribute__((address_space(1))) void*)g,
                                     (__attribute__((address_space(3))) void*)l,
                                     16, 0, 0);
}

__device__ __forceinline__ f32x16 zero16() {
    f32x16 z;
#pragma unroll
    for (int i = 0; i < 16; ++i) z[i] = 0.f;
    return z;
}

// P (f32, C-layout of S^T, 32 rel keys) -> two PV B-operand fragments.
__device__ __forceinline__ void makePB(const f32x16 s, short8& f0, short8& f1) {
    union { unsigned int u[4]; short8 s8; } t;
    {
        unsigned int A0 = cvtpk(s[0], s[1]), A1 = cvtpk(s[2], s[3]);
        unsigned int B0 = cvtpk(s[4], s[5]), B1 = cvtpk(s[6], s[7]);
        uint2v w0 = __builtin_amdgcn_permlane32_swap(A0, B0, false, false);
        uint2v w1 = __builtin_amdgcn_permlane32_swap(A1, B1, false, false);
        t.u[0] = w0[0]; t.u[1] = w1[0]; t.u[2] = w0[1]; t.u[3] = w1[1];
        f0 = t.s8;
    }
    {
        unsigned int A0 = cvtpk(s[8], s[9]), A1 = cvtpk(s[10], s[11]);
        unsigned int B0 = cvtpk(s[12], s[13]), B1 = cvtpk(s[14], s[15]);
        uint2v w0 = __builtin_amdgcn_permlane32_swap(A0, B0, false, false);
        uint2v w1 = __builtin_amdgcn_permlane32_swap(A1, B1, false, false);
        t.u[0] = w0[0]; t.u[1] = w1[0]; t.u[2] = w0[1]; t.u[3] = w1[1];
        f1 = t.s8;
    }
}

// fp32 -> bf16 (RNE), 8 elems/thread
__global__ __launch_bounds__(256) void cast_bf16(const float* __restrict__ src,
                                                 unsigned short* __restrict__ dst,
                                                 int n) {
    int i = (blockIdx.x * 256 + threadIdx.x) * 8;
    if (i >= n) return;
    float4 a = *(const float4*)(src + i);
    float4 b = *(const float4*)(src + i + 4);
    short8 v;
    v[0] = (short)f2b(a.x); v[1] = (short)f2b(a.y);
    v[2] = (short)f2b(a.z); v[3] = (short)f2b(a.w);
    v[4] = (short)f2b(b.x); v[5] = (short)f2b(b.y);
    v[6] = (short)f2b(b.z); v[7] = (short)f2b(b.w);
    *(short8*)(dst + i) = v;
}

// ---------------------------------------------------------------------------
// bf16 MFMA GEMM (NT): out = A @ W^T. 128x128 tile, BK=32, 4 waves.
// MODE 0: fused QKV, W = [Wq;Wk;Wv] (N=3072); scatter bf16 to [3][B,H,S,D];
//         Q part scaled by QSCALE.
// MODE 1: N=1024, fp32 out [M,N] + bias.
// ---------------------------------------------------------------------------
template <int MODE>
__global__ __launch_bounds__(256) void gemm_bf16(const unsigned short* __restrict__ A,
                                                 const unsigned short* __restrict__ W,
                                                 void* __restrict__ outp,
                                                 const float* __restrict__ bias) {
    const int K_ = EMBED;
    __shared__ __attribute__((aligned(16))) unsigned short As[128 * 32];
    __shared__ __attribute__((aligned(16))) unsigned short Bs[128 * 32];

    const int tid  = threadIdx.x;
    const int lane = tid & 63;
    const int w    = tid >> 6;
    const int wr   = w >> 1, wc = w & 1;
    const int m0 = blockIdx.y * 128, n0 = blockIdx.x * 128;

    const unsigned short* gA = A + (size_t)(m0 + w * 32 + (lane >> 2)) * K_ + (lane & 3) * 8;
    const unsigned short* gB = W + (size_t)(n0 + w * 32 + (lane >> 2)) * K_ + (lane & 3) * 8;
    unsigned short* lA = As + (w * 32) * 32;
    unsigned short* lB = Bs + (w * 32) * 32;

    f32x4 zero = {0.f, 0.f, 0.f, 0.f};
    f32x4 acc[4][4];
#pragma unroll
    for (int i = 0; i < 4; ++i)
#pragma unroll
        for (int j = 0; j < 4; ++j) acc[i][j] = zero;

    for (int k0 = 0; k0 < K_; k0 += 32) {
        gld16(gA, lA);
        gld16(gA + (size_t)16 * K_, lA + 16 * 32);
        gld16(gB, lB);
        gld16(gB + (size_t)16 * K_, lB + 16 * 32);
        gA += 32; gB += 32;
        __syncthreads();
        short8 af[4], bfr[4];
#pragma unroll
        for (int i = 0; i < 4; ++i) {
            af[i]  = *(const short8*)&As[(wr * 64 + i * 16 + (lane & 15)) * 32 + (lane >> 4) * 8];
            bfr[i] = *(const short8*)&Bs[(wc * 64 + i * 16 + (lane & 15)) * 32 + (lane >> 4) * 8];
        }
#pragma unroll
        for (int i = 0; i < 4; ++i)
#pragma unroll
            for (int j = 0; j < 4; ++j)
                acc[i][j] = __builtin_amdgcn_mfma_f32_16x16x32_bf16(af[i], bfr[j], acc[i][j], 0, 0, 0);
        __syncthreads();
    }

    if (MODE == 0) {
        const size_t PP = (size_t)BATCH * SEQ * EMBED;
        unsigned short* dst = (unsigned short*)outp;
#pragma unroll
        for (int i = 0; i < 4; ++i)
#pragma unroll
            for (int ni = 0; ni < 4; ++ni) {
                int n = n0 + wc * 64 + ni * 16 + (lane & 15);
                int which = n >> 10;  // 0=Q 1=K 2=V
                int h = (n >> 6) & 15, d = n & 63;
                float os = (which == 0) ? QSCALE : 1.0f;
#pragma unroll
                for (int j = 0; j < 4; ++j) {
                    int m = m0 + wr * 64 + i * 16 + (lane >> 4) * 4 + j;
                    int b = m >> 11, s = m & (SEQ - 1);
                    dst[(size_t)which * PP + (((size_t)b * HEADS + h) * SEQ + s) * HDIM + d] =
                        f2b(acc[i][ni][j] * os);
                }
            }
    } else {
        float* dst = (float*)outp;
#pragma unroll
        for (int i = 0; i < 4; ++i)
#pragma unroll
            for (int ni = 0; ni < 4; ++ni) {
                int n = n0 + wc * 64 + ni * 16 + (lane & 15);
                float bv = bias[n];
#pragma unroll
                for (int j = 0; j < 4; ++j) {
                    int m = m0 + wr * 64 + i * 16 + (lane >> 4) * 4 + j;
                    dst[(size_t)m * EMBED + n] = acc[i][ni][j] + bv;
                }
            }
    }
}

// ---------------------------------------------------------------------------
// Flash attention, 32x32 swapped-QK, causal-balanced: block handles q-tiles
// qtA = 15-bx (heavy) then qtB = bx (light) -> uniform 17 iterations.
// KVBLK=128: K via global_load_lds (pre-swizzled source), V^T reg-staged,
// both double-buffered. Softmax in-register: tree max/sum, defer-max (T13),
// P->PV via cvt_pk + permlane32_swap (T12). exp2 domain.
// ---------------------------------------------------------------------------
__global__ __launch_bounds__(256, 2) void attn_mfma32(const unsigned short* __restrict__ Q,
                                                      const unsigned short* __restrict__ K,
                                                      const unsigned short* __restrict__ V,
                                                      unsigned short* __restrict__ att) {
    __shared__ __attribute__((aligned(16))) unsigned short KsL[2][KVBLK * 64];  // 32 KB
    __shared__ __attribute__((aligned(16))) unsigned short VtL[2][64 * KVBLK];  // 32 KB

    const int tid  = threadIdx.x;
    const int lane = tid & 63;
    const int wv   = tid >> 6;
    const int hi   = lane >> 5;
    const int lq   = lane & 31;
    const int bh   = blockIdx.y;
    const int qtA  = (NQT - 1) - blockIdx.x;  // heavy pass
    const int qtB  = blockIdx.x;              // light pass
    const size_t base = (size_t)bh * SEQ * HDIM;

    // K staging: thread -> row krow (+32j), byte-slot pre-XORed in global addr
    const int krow = tid >> 3;
    const int kxor = ((tid & 7) ^ (krow & 7)) * 8;
    // V staging: thread -> key-pair vkp, d-octets vo, vo+1
    const int vkp = tid & 63, vo = (tid >> 6) * 2;

    const int ksw = (lq & 7) << 4;

    short8 qf[4];
    auto loadQ = [&](int qt) {
        const unsigned short* qrow =
            Q + base + (size_t)(qt * QBLK + wv * 32 + lq) * HDIM + hi * 8;
        qf[0] = *(const short8*)(qrow);
        qf[1] = *(const short8*)(qrow + 16);
        qf[2] = *(const short8*)(qrow + 32);
        qf[3] = *(const short8*)(qrow + 48);
    };

    auto stageK = [&](int k0, int bufi) {
        const unsigned short* g0 = K + base + (size_t)(k0 + krow) * HDIM + kxor;
        unsigned short* l0 = &KsL[bufi][wv * 512];
#pragma unroll
        for (int j = 0; j < 4; ++j)
            gld16(g0 + (size_t)(32 * j) * HDIM, l0 + j * 2048);
    };

    short8 va0, vb0, va1, vb1;
    auto loadV = [&](int k0) {
        const unsigned short* vp = V + base + (size_t)(k0 + 2 * vkp) * HDIM;
        va0 = *(const short8*)(vp + vo * 8);
        vb0 = *(const short8*)(vp + HDIM + vo * 8);
        va1 = *(const short8*)(vp + (vo + 1) * 8);
        vb1 = *(const short8*)(vp + HDIM + (vo + 1) * 8);
    };
    auto writeV = [&](int bufi) {
        char* vb_ = (char*)&VtL[bufi][0];
#pragma unroll
        for (int e = 0; e < 8; ++e) {
            unsigned int p0 = (unsigned int)(unsigned short)va0[e] |
                              ((unsigned int)(unsigned short)vb0[e] << 16);
            *(unsigned int*)(vb_ + ((vo * 8 + e) << 8) + ((4 * vkp) ^ (e << 4))) = p0;
            unsigned int p1 = (unsigned int)(unsigned short)va1[e] |
                              ((unsigned int)(unsigned short)vb1[e] << 16);
            *(unsigned int*)(vb_ + (((vo + 1) * 8 + e) << 8) + ((4 * vkp) ^ (e << 4))) = p1;
        }
    };

    f32x16 o0 = zero16(), o1 = zero16();
    float m_run = -INFINITY, l_run = 0.f;

    const int b_ = bh >> 4, h_ = bh & 15;
    auto writeOut = [&](int q0w_) {
        const float invl = 1.f / l_run;
        unsigned short* orow =
            att + ((size_t)b_ * SEQ + (q0w_ + lq)) * EMBED + h_ * HDIM + 4 * hi;
#pragma unroll
        for (int c = 0; c < 4; ++c) {
            unsigned int w0 = cvtpk(o0[4 * c] * invl, o0[4 * c + 1] * invl);
            unsigned int w1 = cvtpk(o0[4 * c + 2] * invl, o0[4 * c + 3] * invl);
            *(uint2*)(orow + 8 * c) = make_uint2(w0, w1);
            unsigned int w2 = cvtpk(o1[4 * c] * invl, o1[4 * c + 1] * invl);
            unsigned int w3 = cvtpk(o1[4 * c + 2] * invl, o1[4 * c + 3] * invl);
            *(uint2*)(orow + 32 + 8 * c) = make_uint2(w2, w3);
        }
    };

    // ---- prologue ----
    loadQ(qtA);
    int qtCur = qtA;
    int q0w = qtA * QBLK + wv * 32;
    int qsel = q0w + lq;
    stageK(0, 0);
    loadV(0);
    writeV(0);
    __syncthreads();

    const int niter = NQT + 1;  // (qtA+1) + (qtB+1) = 17
    for (int i = 0; i < niter; ++i) {
        const int buf = i & 1, nbuf = buf ^ 1;
        const int kt = (i <= qtA) ? i : (i - qtA - 1);
        const int k0 = kt * KVBLK;
        const bool pf = (i + 1 < niter);

        if (pf) {  // issue next tile's loads early (T14)
            const int ktN = (i + 1 <= qtA) ? (i + 1) : (i - qtA);
            const int k0N = ktN * KVBLK;
            stageK(k0N, nbuf);
            loadV(k0N);
        }

        // ---- QK^T: S^T[key][q] in 4 reg-tiles of 32 keys ----
        const char* kbase = (const char*)&KsL[buf][0];
        f32x16 sS[4];
        __builtin_amdgcn_s_setprio(1);
#pragma unroll
        for (int c = 0; c < 4; ++c) {
            const char* kb_ = kbase + ((c * 32 + lq) << 7);
            f32x16 acc = zero16();
#pragma unroll
            for (int dc = 0; dc < 4; ++dc) {
                short8 kf = *(const short8*)(kb_ + ((((dc << 1) | hi) << 4) ^ ksw));
                acc = __builtin_amdgcn_mfma_f32_32x32x16_bf16(kf, qf[dc], acc, 0, 0, 0);
            }
            sS[c] = acc;
        }
        __builtin_amdgcn_s_setprio(0);

        // ---- causal mask (diagonal tile only) ----
        if (kt == qtCur) {
#pragma unroll
            for (int c = 0; c < 4; ++c)
#pragma unroll
                for (int r = 0; r < 16; ++r) {
                    int key = k0 + 32 * c + (r & 3) + 8 * (r >> 2) + 4 * hi;
                    if (key > qsel) sS[c][r] = -INFINITY;
                }
        }

        // ---- online softmax: tree max, defer-max, exp2, tree sum ----
        f32x16 t;
#pragma unroll
        for (int r = 0; r < 16; ++r)
            t[r] = fmaxf(fmaxf(sS[0][r], sS[1][r]), fmaxf(sS[2][r], sS[3][r]));
        float m8[8];
#pragma unroll
        for (int r = 0; r < 8; ++r) m8[r] = fmaxf(t[r], t[r + 8]);
        float m4[4];
#pragma unroll
        for (int r = 0; r < 4; ++r) m4[r] = fmaxf(m8[r], m8[r + 4]);
        float mx = fmaxf(fmaxf(m4[0], m4[1]), fmaxf(m4[2], m4[3]));
        mx = fmaxf(mx, __shfl_xor(mx, 32));

        if (__any(mx > m_run + 8.0f)) {  // T13: rescale only when max grows
            float mnew = fmaxf(m_run, mx);
            float scl = __builtin_exp2f(m_run - mnew);
            m_run = mnew;
            l_run *= scl;
#pragma unroll
            for (int r = 0; r < 16; ++r) { o0[r] *= scl; o1[r] *= scl; }
        }

#pragma unroll
        for (int c = 0; c < 4; ++c)
#pragma unroll
            for (int r = 0; r < 16; ++r)
                sS[c][r] = __builtin_exp2f(sS[c][r] - m_run);

        f32x16 u;
#pragma unroll
        for (int r = 0; r < 16; ++r)
            u[r] = (sS[0][r] + sS[1][r]) + (sS[2][r] + sS[3][r]);
        float s8[8];
#pragma unroll
        for (int r = 0; r < 8; ++r) s8[r] = u[r] + u[r + 8];
        float s4[4];
#pragma unroll
        for (int r = 0; r < 4; ++r) s4[r] = s8[r] + s8[r + 4];
        float ps = (s4[0] + s4[1]) + (s4[2] + s4[3]);
        ps += __shfl_xor(ps, 32);
        l_run += ps;

        // ---- PV: O^T += V^T x P^T, per 32-key subtile ----
        const char* vtb = (const char*)&VtL[buf][0];
        __builtin_amdgcn_s_setprio(1);
#pragma unroll
        for (int c = 0; c < 4; ++c) {
            short8 pb0, pb1;
            makePB(sS[c], pb0, pb1);
            short8 vf;
            vf = *(const short8*)(vtb + (lq << 8) + ((c * 64 + hi * 16) ^ ksw));
            o0 = __builtin_amdgcn_mfma_f32_32x32x16_bf16(vf, pb0, o0, 0, 0, 0);
            vf = *(const short8*)(vtb + (lq << 8) + ((c * 64 + 32 + hi * 16) ^ ksw));
            o0 = __builtin_amdgcn_mfma_f32_32x32x16_bf16(vf, pb1, o0, 0, 0, 0);
            vf = *(const short8*)(vtb + ((32 + lq) << 8) + ((c * 64 + hi * 16) ^ ksw));
            o1 = __builtin_amdgcn_mfma_f32_32x32x16_bf16(vf, pb0, o1, 0, 0, 0);
            vf = *(const short8*)(vtb + ((32 + lq) << 8) + ((c * 64 + 32 + hi * 16) ^ ksw));
            o1 = __builtin_amdgcn_mfma_f32_32x32x16_bf16(vf, pb1, o1, 0, 0, 0);
        }
        __builtin_amdgcn_s_setprio(0);

        if (pf) writeV(nbuf);
        __syncthreads();  // drains gld vmcnt; VtL[nbuf] visible; cur reads done

        if (i == qtA) {  // pass A finished -> emit, reset, switch to pass B
            writeOut(q0w);
            o0 = zero16(); o1 = zero16();
            m_run = -INFINITY; l_run = 0.f;
            loadQ(qtB);
            qtCur = qtB;
            q0w = qtB * QBLK + wv * 32;
            qsel = q0w + lq;
        }
    }
    writeOut(q0w);
}

// ---------------------------------------------------------------------------
extern "C" void kernel_launch(void* const* d_in, const int* in_sizes, int n_in,
                              void* d_out, int out_size, void* d_ws, size_t ws_size,
                              hipStream_t stream) {
    const float* x  = (const float*)d_in[0];
    const float* Wq = (const float*)d_in[1];
    const float* Wk = (const float*)d_in[2];
    const float* Wv = (const float*)d_in[3];
    const float* Wo = (const float*)d_in[4];
    const float* bo = (const float*)d_in[5];

    const size_t XN = (size_t)BATCH * SEQ * EMBED;  // 8388608
    const size_t WN = (size_t)EMBED * EMBED;        // 1048576

    unsigned short* ws   = (unsigned short*)d_ws;
    unsigned short* xb   = ws;
    unsigned short* wqkv = xb + XN;        // [3*1024][1024]
    unsigned short* wob  = wqkv + 3 * WN;
    unsigned short* Qb   = wob + WN;       // [B,H,S,D]; Kb, Vb follow
    unsigned short* attb = Qb + 3 * XN;    // [B,S,E]

    cast_bf16<<<(int)(XN / 2048), 256, 0, stream>>>(x, xb, (int)XN);
    cast_bf16<<<(int)(WN / 2048), 256, 0, stream>>>(Wq, wqkv, (int)WN);
    cast_bf16<<<(int)(WN / 2048), 256, 0, stream>>>(Wk, wqkv + WN, (int)WN);
    cast_bf16<<<(int)(WN / 2048), 256, 0, stream>>>(Wv, wqkv + 2 * WN, (int)WN);
    cast_bf16<<<(int)(WN / 2048), 256, 0, stream>>>(Wo, wob, (int)WN);

    // fused QKV projection: [8192,1024] x [3072,1024]^T
    gemm_bf16<0><<<dim3(3 * EMBED / 128, BATCH * SEQ / 128), 256, 0, stream>>>(
        xb, wqkv, Qb, nullptr);

    attn_mfma32<<<dim3(NQT / 2, BATCH * HEADS), 256, 0, stream>>>(
        Qb, Qb + XN, Qb + 2 * XN, attb);

    gemm_bf16<1><<<dim3(EMBED / 128, BATCH * SEQ / 128), 256, 0, stream>>>(
        attb, wob, d_out, bo);
}